// Round 3
// baseline (142.632 us; speedup 1.0000x reference)
//
#include <hip/hip_runtime.h>
#include <math.h>

#define NF    64      // filters
#define KT    402     // taps: arange(-201, 201)  (note: -401//2 = -201 in Python)
#define LIN   16000   // input length
#define LOUT  15599   // LIN - KT + 1
#define NB    16      // batch
#define FT    16      // filters per block (per filter-group)
#define TT    256     // output positions per block

// Filter bank in a static __device__ global (no d_ws dependency, no hipMalloc).
// Two planes: [0][k][f] = re, [1][k][f] = im. For a fixed tap k, one
// 16-filter group's 16 floats are contiguous and thread-uniform (64 B).
__device__ float g_filt[2 * KT * NF];

__global__ void gabor_build_filters(const float* __restrict__ cf,
                                    const float* __restrict__ bw) {
    int idx = blockIdx.x * blockDim.x + threadIdx.x;
    if (idx >= NF * KT) return;
    int f = idx & (NF - 1);
    int k = idx >> 6;               // 0..401
    float t = (float)(k - 201);     // -201 .. 200
    float b = bw[f];
    float env = expf(-(t * t) / (2.0f * b * b)) / (sqrtf(2.0f * (float)M_PI) * b);
    float s, c;
    sincosf(cf[f] * t, &s, &c);
    g_filt[idx]           = env * c;    // re plane
    g_filt[KT * NF + idx] = env * s;    // im plane
}

// One block: one batch b, one filter-group g (16 filters), 256 output
// positions. Each thread: 1 position, 16 filters. Per tap k: 1 LDS read of x
// (stride-1, conflict-free) + 16 (real) or 32 (complex) FMAs against
// thread-uniform coefficients.
// CPLX chosen at launch from out_size: the harness's d_out may hold either
// the real part only (complex64 -> float32 "else float*" mapping) or
// interleaved re/im. ALL writes are bounds-guarded by out_elems.
template <bool CPLX>
__global__ __launch_bounds__(TT) void gabor_conv(const float* __restrict__ x,
                                                 float* __restrict__ out,
                                                 long out_elems) {
    __shared__ float sx[TT + KT];       // 658 floats

    const int tile = blockIdx.x;        // 0..60
    const int g    = blockIdx.y;        // 0..3
    const int b    = blockIdx.z;        // 0..15
    const int t0   = tile * TT;

    const float* __restrict__ xb = x + (size_t)b * LIN;
    for (int i = threadIdx.x; i < TT + KT - 1; i += TT) {
        int idx = t0 + i;
        sx[i] = (idx < LIN) ? xb[idx] : 0.0f;
    }
    __syncthreads();

    float accre[FT];
    float accim[CPLX ? FT : 1];
#pragma unroll
    for (int j = 0; j < FT; ++j) accre[j] = 0.0f;
    if constexpr (CPLX) {
#pragma unroll
        for (int j = 0; j < FT; ++j) accim[j] = 0.0f;
    }

    const float* __restrict__ fre = g_filt + g * FT;
    const float* __restrict__ fim = g_filt + KT * NF + g * FT;

#pragma unroll 2
    for (int k = 0; k < KT; ++k) {
        float xv = sx[threadIdx.x + k];
        const float* fr = fre + k * NF;
#pragma unroll
        for (int j = 0; j < FT; ++j)
            accre[j] = __builtin_fmaf(xv, fr[j], accre[j]);
        if constexpr (CPLX) {
            const float* fi = fim + k * NF;
#pragma unroll
            for (int j = 0; j < FT; ++j)
                accim[j] = __builtin_fmaf(xv, fi[j], accim[j]);
        }
    }

    const int t = t0 + (int)threadIdx.x;
    if (t < LOUT) {
#pragma unroll
        for (int j = 0; j < FT; ++j) {
            int f = g * FT + j;
            size_t base = (size_t)(b * NF + f) * LOUT + t;
            if constexpr (CPLX) {
                size_t o = base * 2;
                if ((long)(o + 1) < out_elems) {
                    float2 v;
                    v.x = accre[j];
                    v.y = accim[j];
                    *reinterpret_cast<float2*>(out + o) = v;
                }
            } else {
                if ((long)base < out_elems) out[base] = accre[j];
            }
        }
    }
}

extern "C" void kernel_launch(void* const* d_in, const int* in_sizes, int n_in,
                              void* d_out, int out_size, void* d_ws, size_t ws_size,
                              hipStream_t stream) {
    const float* x  = (const float*)d_in[0];
    const float* cf = (const float*)d_in[1];
    const float* bw = (const float*)d_in[2];
    float* out = (float*)d_out;
    (void)d_ws; (void)ws_size;

    {
        int n = NF * KT;
        gabor_build_filters<<<(n + 255) / 256, 256, 0, stream>>>(cf, bw);
    }

    const long n_complex = (long)NB * NF * LOUT;   // 15,973,376
    const bool cplx = ((long)out_size >= 2 * n_complex);

    dim3 grid((LOUT + TT - 1) / TT, NF / FT, NB);  // (61, 4, 16)
    if (cplx)
        gabor_conv<true><<<grid, TT, 0, stream>>>(x, out, (long)out_size);
    else
        gabor_conv<false><<<grid, TT, 0, stream>>>(x, out, (long)out_size);
}

// Round 4
// 86.673 us; speedup vs baseline: 1.6456x; 1.6456x over previous
//
#include <hip/hip_runtime.h>
#include <math.h>

#define NF    64      // filters
#define KT    402     // taps: arange(-201, 201)  (-401//2 = -201 in Python)
#define LIN   16000   // input length
#define LOUT  15599   // LIN - KT + 1
#define NB    16      // batch
#define FT    16      // filters per block (per filter-group)
#define TT    256     // output positions per block

// Filter bank in a static __device__ global. Two planes: [0][k][f] = re,
// [1][k][f] = im, k = 0..401 (t = k-201). For fixed k, one 16-filter group's
// 16 floats are contiguous + thread-uniform -> one s_load_dwordx16 per tap.
// Symmetry (used by the conv): re[k] == re[402-k], im[k] == -im[402-k].
__device__ float g_filt[2 * KT * NF];

__global__ void gabor_build_filters(const float* __restrict__ cf,
                                    const float* __restrict__ bw) {
    int idx = blockIdx.x * blockDim.x + threadIdx.x;
    if (idx >= NF * KT) return;
    int f = idx & (NF - 1);
    int k = idx >> 6;               // 0..401
    float t = (float)(k - 201);     // -201 .. 200
    float b = bw[f];
    float env = expf(-(t * t) / (2.0f * b * b)) / (sqrtf(2.0f * (float)M_PI) * b);
    float s, c;
    sincosf(cf[f] * t, &s, &c);
    g_filt[idx]           = env * c;    // re plane
    g_filt[KT * NF + idx] = env * s;    // im plane
}

// One block: one batch b, one filter-group g (16 filters), 256 positions.
// Folded conv: out_re[n] = c0*x[n] + c201*x[n+201]
//                        + sum_{p=1..200} c[p]*(x[n+p] + x[n+402-p])
// (im plane antisymmetric: uses (x1 - x2), im[201] = sin(0) = 0.)
// Per pair: 2 LDS reads (stride-1, conflict-free) + 1 add + 16 FMA against
// thread-uniform coefficients (scalar loads, off the VALU pipe).
template <bool CPLX>
__global__ __launch_bounds__(TT) void gabor_conv(const float* __restrict__ x,
                                                 float* __restrict__ out,
                                                 long out_elems) {
    __shared__ float sx[TT + KT];       // 658 floats

    const int tile = blockIdx.x;        // 0..60
    const int g    = blockIdx.y;        // 0..3
    const int b    = blockIdx.z;        // 0..15
    const int t0   = tile * TT;
    const int tid  = threadIdx.x;

    const float* __restrict__ xb = x + (size_t)b * LIN;
    for (int i = tid; i < TT + KT - 1; i += TT) {
        int idx = t0 + i;
        sx[i] = (idx < LIN) ? xb[idx] : 0.0f;
    }
    __syncthreads();

    const float* __restrict__ fre = g_filt + g * FT;
    const float* __restrict__ fim = g_filt + KT * NF + g * FT;

    float accre[FT];
    float accim[CPLX ? FT : 1];

    // Unpaired taps: k=0 (t=-201) and k=201 (t=0; im coefficient = 0).
    {
        float x0 = sx[tid];
        float xm = sx[tid + 201];
        const float* c0 = fre;
        const float* cm = fre + 201 * NF;
#pragma unroll
        for (int j = 0; j < FT; ++j)
            accre[j] = __builtin_fmaf(xm, cm[j], x0 * c0[j]);
        if constexpr (CPLX) {
            const float* ci0 = fim;
#pragma unroll
            for (int j = 0; j < FT; ++j)
                accim[j] = x0 * ci0[j];
        }
    }

    // 200 symmetric pairs (p, 402-p).
#pragma unroll 2
    for (int p = 1; p <= 200; ++p) {
        float x1 = sx[tid + p];
        float x2 = sx[tid + 402 - p];
        float xs = x1 + x2;
        const float* cr = fre + p * NF;
#pragma unroll
        for (int j = 0; j < FT; ++j)
            accre[j] = __builtin_fmaf(xs, cr[j], accre[j]);
        if constexpr (CPLX) {
            float xd = x1 - x2;
            const float* ci = fim + p * NF;
#pragma unroll
            for (int j = 0; j < FT; ++j)
                accim[j] = __builtin_fmaf(xd, ci[j], accim[j]);
        }
    }

    const int t = t0 + tid;
    if (t < LOUT) {
#pragma unroll
        for (int j = 0; j < FT; ++j) {
            int f = g * FT + j;
            size_t base = (size_t)(b * NF + f) * LOUT + t;
            if constexpr (CPLX) {
                size_t o = base * 2;
                if ((long)(o + 1) < out_elems) {
                    float2 v;
                    v.x = accre[j];
                    v.y = accim[j];
                    *reinterpret_cast<float2*>(out + o) = v;
                }
            } else {
                if ((long)base < out_elems) out[base] = accre[j];
            }
        }
    }
}

extern "C" void kernel_launch(void* const* d_in, const int* in_sizes, int n_in,
                              void* d_out, int out_size, void* d_ws, size_t ws_size,
                              hipStream_t stream) {
    const float* x  = (const float*)d_in[0];
    const float* cf = (const float*)d_in[1];
    const float* bw = (const float*)d_in[2];
    float* out = (float*)d_out;
    (void)d_ws; (void)ws_size;

    {
        int n = NF * KT;
        gabor_build_filters<<<(n + 255) / 256, 256, 0, stream>>>(cf, bw);
    }

    const long n_complex = (long)NB * NF * LOUT;   // 15,973,376
    const bool cplx = ((long)out_size >= 2 * n_complex);

    dim3 grid((LOUT + TT - 1) / TT, NF / FT, NB);  // (61, 4, 16)
    if (cplx)
        gabor_conv<true><<<grid, TT, 0, stream>>>(x, out, (long)out_size);
    else
        gabor_conv<false><<<grid, TT, 0, stream>>>(x, out, (long)out_size);
}

// Round 5
// 70.859 us; speedup vs baseline: 2.0129x; 1.2232x over previous
//
#include <hip/hip_runtime.h>
#include <math.h>

#define NF    64      // filters
#define KT    402     // taps: arange(-201, 201)
#define KP    416     // padded taps = 13 * 32
#define NSTEP 13      // K-steps of 32
#define LIN   16000
#define LOUT  15599   // LIN - KT + 1
#define NB    16
#define NT    128     // output positions per block (8 subtiles x 16)
#define NSUB  8
#define SPAN  544     // NT + KP data span per block
#define SROW  552     // padded LDS row stride (elems): 1104 B = 20 dwords mod 32 banks
#define TT    256

typedef __attribute__((ext_vector_type(8))) short short8;   // 8 bf16 (4 VGPR)
typedef __attribute__((ext_vector_type(4))) float f32x4;    // MFMA acc

// fp32 planes [plane][k][f] for the complex fallback path (as in R4).
__device__ float g_filt[2 * KT * NF];
// bf16 hi/lo split of the REAL coefficients, [hi/lo][f][k], k padded w/ zeros.
__device__ __align__(16) short g_cb[2][NF][KP];

__device__ __forceinline__ short f2bf(float v) {
    unsigned u = __float_as_uint(v);
    unsigned r = (u + 0x7fffu + ((u >> 16) & 1u)) >> 16;   // RNE
    return (short)r;
}
__device__ __forceinline__ float bf2f(short s) {
    return __uint_as_float(((unsigned)(unsigned short)s) << 16);
}

__global__ void gabor_build_filters(const float* __restrict__ cf,
                                    const float* __restrict__ bw) {
    int idx = blockIdx.x * blockDim.x + threadIdx.x;    // f*KP + k
    if (idx >= NF * KP) return;
    int f = idx / KP;
    int k = idx - f * KP;
    float cre = 0.0f;
    if (k < KT) {
        float t = (float)(k - 201);
        float b = bw[f];
        float env = expf(-(t * t) / (2.0f * b * b)) / (sqrtf(2.0f * (float)M_PI) * b);
        float s, c;
        sincosf(cf[f] * t, &s, &c);
        cre = env * c;
        g_filt[k * NF + f]           = cre;      // re plane (fallback)
        g_filt[KT * NF + k * NF + f] = env * s;  // im plane (fallback)
    }
    short hi = f2bf(cre);
    g_cb[0][f][k] = hi;
    g_cb[1][f][k] = f2bf(cre - bf2f(hi));
}

// MFMA implicit GEMM, real part only.
// Per block: 128 positions x 64 filters x batch b. 4 waves; wave w = filters
// 16w..16w+15 (B operand in registers), loops 8 position-subtiles.
// A operand (Hankel of x) from LDS via 8 shifted bf16 copies so every
// fragment is one aligned ds_read_b128. 3-term bf16 split emulates fp32.
__global__ __launch_bounds__(TT) void gabor_conv_mfma(const float* __restrict__ x,
                                                      float* __restrict__ out,
                                                      long out_elems) {
    __shared__ __align__(16) short sxh[8][SROW];
    __shared__ __align__(16) short sxl[8][SROW];

    const int tile = blockIdx.x;
    const int b    = blockIdx.y;
    const int n0   = tile * NT;
    const int tid  = threadIdx.x;
    const int wid  = tid >> 6;
    const int lane = tid & 63;

    const float* __restrict__ xb = x + (size_t)b * LIN;

    // Stage x tile -> bf16 hi/lo, 8 shifted copies each: copy c holds
    // element (i) at index (i - c), so any 8-consecutive read whose start
    // e0 satisfies e0 mod 8 == c is 16B-aligned in copy c.
    for (int i = tid; i < SPAN; i += TT) {
        int gi = n0 + i;
        float v = (gi < LIN) ? xb[gi] : 0.0f;
        short hs = f2bf(v);
        short ls = f2bf(v - bf2f(hs));
#pragma unroll
        for (int c = 0; c < 8; ++c) {
            int ti = i - c;
            if (ti >= 0) { sxh[c][ti] = hs; sxl[c][ti] = ls; }
        }
    }

    // B fragments (coefficients) -> registers. Lane holds filter f = f0+(lane&15),
    // taps 32s + 8*(lane>>4) .. +7 (8 consecutive bf16 = one dwordx4).
    const int f0 = wid * 16;
    const int fl = f0 + (lane & 15);
    const int kb = (lane >> 4) * 8;
    short8 bh[NSTEP], bl[NSTEP];
    {
        const short* gb0 = &g_cb[0][fl][kb];
        const short* gb1 = &g_cb[1][fl][kb];
#pragma unroll
        for (int s = 0; s < NSTEP; ++s) {
            bh[s] = *(const short8*)(gb0 + 32 * s);
            bl[s] = *(const short8*)(gb1 + 32 * s);
        }
    }

    __syncthreads();

    // A-read per-lane constant part: copy row (lane&7), element offset
    // 8*(lane>>4) + 8*((lane>>3)&1); loop adds 16n + 32s.
    const int c8    = lane & 7;
    const int abase = 8 * (lane >> 4) + 8 * ((lane >> 3) & 1);
    const short* ah_base = &sxh[c8][abase];
    const short* al_base = &sxl[c8][abase];

    const size_t rowbase = (size_t)(b * NF + fl) * LOUT;

#pragma unroll
    for (int n = 0; n < NSUB; ++n) {
        f32x4 acc = {0.0f, 0.0f, 0.0f, 0.0f};
#pragma unroll
        for (int s = 0; s < NSTEP; ++s) {
            const int off = 16 * n + 32 * s;
            short8 ah = *(const short8*)(ah_base + off);
            short8 al = *(const short8*)(al_base + off);
            acc = __builtin_amdgcn_mfma_f32_16x16x32_bf16(ah, bh[s], acc, 0, 0, 0);
            acc = __builtin_amdgcn_mfma_f32_16x16x32_bf16(al, bh[s], acc, 0, 0, 0);
            acc = __builtin_amdgcn_mfma_f32_16x16x32_bf16(ah, bl[s], acc, 0, 0, 0);
        }
        // D: col = lane&15 = filter, row = 4*(lane>>4)+r = position-in-16.
        const int npos0 = n0 + 16 * n + 4 * (lane >> 4);
#pragma unroll
        for (int r = 0; r < 4; ++r) {
            int np = npos0 + r;
            if (np < LOUT) {
                size_t o = rowbase + np;
                if ((long)o < out_elems) out[o] = acc[r];
            }
        }
    }
}

// Complex fallback (R4's folded fp32 kernel) in case d_out is interleaved
// complex. Unused on the real-only harness path but kept correct.
__global__ __launch_bounds__(TT) void gabor_conv_cplx(const float* __restrict__ x,
                                                      float* __restrict__ out,
                                                      long out_elems) {
    __shared__ float sx[TT + KT];
    const int tile = blockIdx.x, g = blockIdx.y, b = blockIdx.z;
    const int t0 = tile * TT, tid = threadIdx.x;
    const float* __restrict__ xb = x + (size_t)b * LIN;
    for (int i = tid; i < TT + KT - 1; i += TT) {
        int idx = t0 + i;
        sx[i] = (idx < LIN) ? xb[idx] : 0.0f;
    }
    __syncthreads();
    const float* fre = g_filt + g * 16;
    const float* fim = g_filt + KT * NF + g * 16;
    float accre[16], accim[16];
    {
        float x0 = sx[tid], xm = sx[tid + 201];
        const float* c0 = fre;
        const float* cm = fre + 201 * NF;
#pragma unroll
        for (int j = 0; j < 16; ++j) accre[j] = __builtin_fmaf(xm, cm[j], x0 * c0[j]);
#pragma unroll
        for (int j = 0; j < 16; ++j) accim[j] = x0 * fim[j];
    }
#pragma unroll 2
    for (int p = 1; p <= 200; ++p) {
        float x1 = sx[tid + p], x2 = sx[tid + 402 - p];
        float xs = x1 + x2, xd = x1 - x2;
        const float* cr = fre + p * NF;
        const float* ci = fim + p * NF;
#pragma unroll
        for (int j = 0; j < 16; ++j) accre[j] = __builtin_fmaf(xs, cr[j], accre[j]);
#pragma unroll
        for (int j = 0; j < 16; ++j) accim[j] = __builtin_fmaf(xd, ci[j], accim[j]);
    }
    const int t = t0 + tid;
    if (t < LOUT) {
#pragma unroll
        for (int j = 0; j < 16; ++j) {
            size_t o = ((size_t)(b * NF + g * 16 + j) * LOUT + t) * 2;
            if ((long)(o + 1) < out_elems) {
                float2 v; v.x = accre[j]; v.y = accim[j];
                *reinterpret_cast<float2*>(out + o) = v;
            }
        }
    }
}

extern "C" void kernel_launch(void* const* d_in, const int* in_sizes, int n_in,
                              void* d_out, int out_size, void* d_ws, size_t ws_size,
                              hipStream_t stream) {
    const float* x  = (const float*)d_in[0];
    const float* cf = (const float*)d_in[1];
    const float* bw = (const float*)d_in[2];
    float* out = (float*)d_out;
    (void)d_ws; (void)ws_size;

    {
        int n = NF * KP;
        gabor_build_filters<<<(n + 255) / 256, 256, 0, stream>>>(cf, bw);
    }

    const long n_complex = (long)NB * NF * LOUT;
    const bool cplx = ((long)out_size >= 2 * n_complex);

    if (cplx) {
        dim3 grid((LOUT + TT - 1) / TT, NF / 16, NB);
        gabor_conv_cplx<<<grid, TT, 0, stream>>>(x, out, (long)out_size);
    } else {
        dim3 grid((LOUT + NT - 1) / NT, NB);   // (122, 16)
        gabor_conv_mfma<<<grid, TT, 0, stream>>>(x, out, (long)out_size);
    }
}

// Round 6
// 56.802 us; speedup vs baseline: 2.5110x; 1.2475x over previous
//
#include <hip/hip_runtime.h>
#include <math.h>

#define NF    64      // filters
#define KT    402     // taps: arange(-201, 201)
#define KP    416     // padded taps = 13 * 32
#define NSTEP 13      // K-steps of 32
#define LIN   16000
#define LOUT  15599   // LIN - KT + 1
#define NB    16
#define NT    128     // output positions per block (8 subtiles x 16)
#define NSUB  8
#define SPAN  544     // NT + KP data span per block
#define NCHUNK 68     // SPAN / 8 staging chunks
#define SROW  552     // LDS copy-row stride (elems): 1104 B; 8-row b128 reads cover all 32 banks
#define TT    256

typedef __attribute__((ext_vector_type(8))) short short8;   // 8 bf16 (4 VGPR)
typedef __attribute__((ext_vector_type(4))) float f32x4;    // MFMA acc

// fp32 planes [plane][k][f] for the complex fallback path.
__device__ float g_filt[2 * KT * NF];
// B operand pre-packed in MFMA fragment order: [plane][group][s][lane][j].
// Value = bf16 split of coef(filter = 16*group + (lane&15),
//                            tap    = 8*(lane>>4) + 32*s + j).
__device__ __align__(16) short g_cbf[2][4][NSTEP][64][8];

__device__ __forceinline__ short f2bf(float v) {
    unsigned u = __float_as_uint(v);
    unsigned r = (u + 0x7fffu + ((u >> 16) & 1u)) >> 16;   // RNE
    return (short)r;
}
__device__ __forceinline__ float bf2f(short s) {
    return __uint_as_float(((unsigned)(unsigned short)s) << 16);
}

__global__ void gabor_build_filters(const float* __restrict__ cf,
                                    const float* __restrict__ bw) {
    int idx = blockIdx.x * blockDim.x + threadIdx.x;    // f*KP + k
    if (idx >= NF * KP) return;
    int f = idx / KP;
    int k = idx - f * KP;
    float cre = 0.0f;
    if (k < KT) {
        float t = (float)(k - 201);
        float b = bw[f];
        float env = expf(-(t * t) / (2.0f * b * b)) / (sqrtf(2.0f * (float)M_PI) * b);
        float s, c;
        sincosf(cf[f] * t, &s, &c);
        cre = env * c;
        g_filt[k * NF + f]           = cre;      // re plane (fallback)
        g_filt[KT * NF + k * NF + f] = env * s;  // im plane (fallback)
    }
    short hi = f2bf(cre);
    short lo = f2bf(cre - bf2f(hi));
    // scatter into fragment order: lane = (f&15) | q<<4, with k = 32s + 8q + j
    int g = f >> 4;
    int s = k >> 5;
    int q = (k >> 3) & 3;
    int j = k & 7;
    int l = (f & 15) | (q << 4);
    g_cbf[0][g][s][l][j] = hi;
    g_cbf[1][g][s][l][j] = lo;
}

// MFMA implicit GEMM, real part only. Per block: 128 positions x 64 filters x
// batch b; 4 waves, wave w = filters 16w..16w+15.
// A (Hankel of x) from LDS: 8 shifted bf16 copies (copy c holds element i at
// index i-c) so every fragment is one aligned ds_read_b128; fragments at
// offset 16m reused across (n,s) with m = n+2s via an 8-slot rolling register
// window (64 reads/wave instead of 208). 3-term bf16 split emulates fp32.
__global__ __launch_bounds__(TT) void gabor_conv_mfma(const float* __restrict__ x,
                                                      float* __restrict__ out,
                                                      long out_elems) {
    __shared__ __align__(16) short sxh[8][SROW];
    __shared__ __align__(16) short sxl[8][SROW];

    const int tile = blockIdx.x;
    const int b    = blockIdx.y;
    const int n0   = tile * NT;
    const int tid  = threadIdx.x;
    const int wid  = tid >> 6;
    const int lane = tid & 63;

    // ---- Vectorized staging: thread j < 68 owns x elements [8j, 8j+16),
    // builds all 8 shifted windows in registers, writes 16 ds_write_b128.
    if (tid < NCHUNK) {
        const int j  = tid;
        const int e0 = 8 * j;
        const float* __restrict__ src = x + (size_t)b * LIN + n0 + e0;

        float xv[16];
        if (n0 + e0 + 16 <= LIN) {
#pragma unroll
            for (int q = 0; q < 4; ++q) {
                float4 v = *reinterpret_cast<const float4*>(src + 4 * q);
                xv[4 * q + 0] = v.x; xv[4 * q + 1] = v.y;
                xv[4 * q + 2] = v.z; xv[4 * q + 3] = v.w;
            }
        } else {
#pragma unroll
            for (int i = 0; i < 16; ++i) {
                int gi = n0 + e0 + i;
                xv[i] = (gi < LIN) ? src[i] : 0.0f;
            }
        }

        unsigned hd[8], ld[8];   // packed bf16 pairs (little-endian: low16 = even elem)
#pragma unroll
        for (int i = 0; i < 8; ++i) {
            unsigned h0 = (unsigned short)f2bf(xv[2 * i]);
            unsigned h1 = (unsigned short)f2bf(xv[2 * i + 1]);
            hd[i] = h0 | (h1 << 16);
            unsigned l0 = (unsigned short)f2bf(xv[2 * i]     - bf2f((short)h0));
            unsigned l1 = (unsigned short)f2bf(xv[2 * i + 1] - bf2f((short)h1));
            ld[i] = l0 | (l1 << 16);
        }

#pragma unroll
        for (int c = 0; c < 8; ++c) {
            unsigned wh[4], wl[4];
            if ((c & 1) == 0) {
#pragma unroll
                for (int i = 0; i < 4; ++i) {
                    wh[i] = hd[c / 2 + i];
                    wl[i] = ld[c / 2 + i];
                }
            } else {
#pragma unroll
                for (int i = 0; i < 4; ++i) {
                    int k2 = (c - 1) / 2 + i;
                    wh[i] = (hd[k2] >> 16) | (hd[k2 + 1] << 16);   // v_alignbit
                    wl[i] = (ld[k2] >> 16) | (ld[k2 + 1] << 16);
                }
            }
            uint4 vh = {wh[0], wh[1], wh[2], wh[3]};
            uint4 vl = {wl[0], wl[1], wl[2], wl[3]};
            *reinterpret_cast<uint4*>(&sxh[c][e0]) = vh;
            *reinterpret_cast<uint4*>(&sxl[c][e0]) = vl;
        }
    }
    __syncthreads();

    // ---- MFMA phase
    const int c8    = lane & 7;
    const int abase = 8 * ((lane >> 3) & 1) + 8 * (lane >> 4);
    const short* ah_base = &sxh[c8][abase];
    const short* al_base = &sxl[c8][abase];

    const short* bhp = &g_cbf[0][wid][0][lane][0];   // stride 512 shorts per s
    const short* blp = &g_cbf[1][wid][0][lane][0];

    short8 Ah[8], Al[8];
#pragma unroll
    for (int m = 0; m < 8; ++m) {
        Ah[m] = *(const short8*)(ah_base + 16 * m);
        Al[m] = *(const short8*)(al_base + 16 * m);
    }

    f32x4 acc[NSUB];
#pragma unroll
    for (int n = 0; n < NSUB; ++n) {
        f32x4 z = {0.0f, 0.0f, 0.0f, 0.0f};
        acc[n] = z;
    }

#pragma unroll
    for (int s = 0; s < NSTEP; ++s) {
        short8 bh = *(const short8*)(bhp + 512 * s);
        short8 bl = *(const short8*)(blp + 512 * s);
#pragma unroll
        for (int n = 0; n < NSUB; ++n) {
            const int slot = (2 * s + n) & 7;
            acc[n] = __builtin_amdgcn_mfma_f32_16x16x32_bf16(Ah[slot], bh, acc[n], 0, 0, 0);
            acc[n] = __builtin_amdgcn_mfma_f32_16x16x32_bf16(Al[slot], bh, acc[n], 0, 0, 0);
            acc[n] = __builtin_amdgcn_mfma_f32_16x16x32_bf16(Ah[slot], bl, acc[n], 0, 0, 0);
        }
        if (s < NSTEP - 1) {   // slide window: slots (2s)&7, (2s+1)&7 -> m = 2s+8, 2s+9
            const int m0 = 2 * s + 8, m1 = 2 * s + 9;
            Ah[m0 & 7] = *(const short8*)(ah_base + 16 * m0);
            Al[m0 & 7] = *(const short8*)(al_base + 16 * m0);
            Ah[m1 & 7] = *(const short8*)(ah_base + 16 * m1);
            Al[m1 & 7] = *(const short8*)(al_base + 16 * m1);
        }
    }

    // D: col = lane&15 = filter, row = 4*(lane>>4)+r = position offset.
    const int fl = wid * 16 + (lane & 15);
    const size_t rowbase = (size_t)(b * NF + fl) * LOUT;
#pragma unroll
    for (int n = 0; n < NSUB; ++n) {
        const int npos0 = n0 + 16 * n + 4 * (lane >> 4);
#pragma unroll
        for (int r = 0; r < 4; ++r) {
            int np = npos0 + r;
            if (np < LOUT) {
                size_t o = rowbase + np;
                if ((long)o < out_elems) out[o] = acc[n][r];
            }
        }
    }
}

// Complex fallback (folded fp32) in case d_out is interleaved complex.
__global__ __launch_bounds__(TT) void gabor_conv_cplx(const float* __restrict__ x,
                                                      float* __restrict__ out,
                                                      long out_elems) {
    __shared__ float sx[TT + KT];
    const int tile = blockIdx.x, g = blockIdx.y, b = blockIdx.z;
    const int t0 = tile * TT, tid = threadIdx.x;
    const float* __restrict__ xb = x + (size_t)b * LIN;
    for (int i = tid; i < TT + KT - 1; i += TT) {
        int idx = t0 + i;
        sx[i] = (idx < LIN) ? xb[idx] : 0.0f;
    }
    __syncthreads();
    const float* fre = g_filt + g * 16;
    const float* fim = g_filt + KT * NF + g * 16;
    float accre[16], accim[16];
    {
        float x0 = sx[tid], xm = sx[tid + 201];
        const float* c0 = fre;
        const float* cm = fre + 201 * NF;
#pragma unroll
        for (int j = 0; j < 16; ++j) accre[j] = __builtin_fmaf(xm, cm[j], x0 * c0[j]);
#pragma unroll
        for (int j = 0; j < 16; ++j) accim[j] = x0 * fim[j];
    }
#pragma unroll 2
    for (int p = 1; p <= 200; ++p) {
        float x1 = sx[tid + p], x2 = sx[tid + 402 - p];
        float xs = x1 + x2, xd = x1 - x2;
        const float* cr = fre + p * NF;
        const float* ci = fim + p * NF;
#pragma unroll
        for (int j = 0; j < 16; ++j) accre[j] = __builtin_fmaf(xs, cr[j], accre[j]);
#pragma unroll
        for (int j = 0; j < 16; ++j) accim[j] = __builtin_fmaf(xd, ci[j], accim[j]);
    }
    const int t = t0 + tid;
    if (t < LOUT) {
#pragma unroll
        for (int j = 0; j < 16; ++j) {
            size_t o = ((size_t)(b * NF + g * 16 + j) * LOUT + t) * 2;
            if ((long)(o + 1) < out_elems) {
                float2 v; v.x = accre[j]; v.y = accim[j];
                *reinterpret_cast<float2*>(out + o) = v;
            }
        }
    }
}

extern "C" void kernel_launch(void* const* d_in, const int* in_sizes, int n_in,
                              void* d_out, int out_size, void* d_ws, size_t ws_size,
                              hipStream_t stream) {
    const float* x  = (const float*)d_in[0];
    const float* cf = (const float*)d_in[1];
    const float* bw = (const float*)d_in[2];
    float* out = (float*)d_out;
    (void)d_ws; (void)ws_size;

    {
        int n = NF * KP;
        gabor_build_filters<<<(n + 255) / 256, 256, 0, stream>>>(cf, bw);
    }

    const long n_complex = (long)NB * NF * LOUT;
    const bool cplx = ((long)out_size >= 2 * n_complex);

    if (cplx) {
        dim3 grid((LOUT + TT - 1) / TT, NF / 16, NB);
        gabor_conv_cplx<<<grid, TT, 0, stream>>>(x, out, (long)out_size);
    } else {
        dim3 grid((LOUT + NT - 1) / NT, NB);   // (122, 16)
        gabor_conv_mfma<<<grid, TT, 0, stream>>>(x, out, (long)out_size);
    }
}

// Round 7
// 55.214 us; speedup vs baseline: 2.5833x; 1.0288x over previous
//
#include <hip/hip_runtime.h>
#include <math.h>

#define NF    64      // filters
#define KT    402     // taps: arange(-201, 201)
#define KP    416     // padded taps = 13 * 32
#define NSTEP 13      // K-steps of 32
#define LIN   16000
#define LOUT  15599   // LIN - KT + 1
#define NB    16
#define NT    128     // output positions per block (8 subtiles x 16)
#define NSUB  8
#define SPAN  544     // NT + KP data span per block
#define NCHUNK 68     // SPAN / 8 staging chunks
#define SROW  552     // LDS copy-row stride (elems): 1104 B; 8-row b128 reads cover all 32 banks
#define TT    256

typedef __attribute__((ext_vector_type(8))) short short8;   // 8 bf16 (4 VGPR)
typedef __attribute__((ext_vector_type(4))) float f32x4;    // MFMA acc

// fp32 planes [plane][k][f] for the complex fallback path.
__device__ float g_filt[2 * KT * NF];
// B operand pre-packed in MFMA fragment order: [plane][group][s][lane][j].
// Value = bf16 split of coef(filter = 16*group + (lane&15),
//                            tap    = 8*(lane>>4) + 32*s + j).
__device__ __align__(16) short g_cbf[2][4][NSTEP][64][8];

__device__ __forceinline__ short f2bf(float v) {
    unsigned u = __float_as_uint(v);
    unsigned r = (u + 0x7fffu + ((u >> 16) & 1u)) >> 16;   // RNE
    return (short)r;
}
__device__ __forceinline__ float bf2f(short s) {
    return __uint_as_float(((unsigned)(unsigned short)s) << 16);
}

__global__ void gabor_build_filters(const float* __restrict__ cf,
                                    const float* __restrict__ bw) {
    int idx = blockIdx.x * blockDim.x + threadIdx.x;    // f*KP + k
    if (idx >= NF * KP) return;
    int f = idx / KP;
    int k = idx - f * KP;
    float cre = 0.0f;
    if (k < KT) {
        float t = (float)(k - 201);
        float b = bw[f];
        float env = expf(-(t * t) / (2.0f * b * b)) / (sqrtf(2.0f * (float)M_PI) * b);
        float s, c;
        sincosf(cf[f] * t, &s, &c);
        cre = env * c;
        g_filt[k * NF + f]           = cre;      // re plane (fallback)
        g_filt[KT * NF + k * NF + f] = env * s;  // im plane (fallback)
    }
    short hi = f2bf(cre);
    short lo = f2bf(cre - bf2f(hi));
    // scatter into fragment order: lane = (f&15) | q<<4, with k = 32s + 8q + j
    int g = f >> 4;
    int s = k >> 5;
    int q = (k >> 3) & 3;
    int j = k & 7;
    int l = (f & 15) | (q << 4);
    g_cbf[0][g][s][l][j] = hi;
    g_cbf[1][g][s][l][j] = lo;
}

// MFMA implicit GEMM, real part only. Per block: 128 positions x 64 filters x
// batch b; 4 waves, wave w = filters 16w..16w+15.
// A (Hankel of x) from LDS via 8 shifted bf16 copies (copy c holds element i
// at index i-c -> every fragment one aligned ds_read_b128); fragments at
// offset 16m (m = n+2s) reused through an 8-slot rolling register window.
// B (coefficients) double-buffered from global: step s issues s+1's 2 global
// loads + 4 window ds_reads BEFORE s's 24 MFMAs (R6 post-mortem: in-loop
// non-pipelined B loads left the loop L2-latency-bound at VGPR=72).
// 3-term bf16 split (Ah*Bh + Al*Bh + Ah*Bl) emulates fp32.
__global__ __launch_bounds__(TT, 3) void gabor_conv_mfma(const float* __restrict__ x,
                                                         float* __restrict__ out,
                                                         long out_elems) {
    __shared__ __align__(16) short sxh[8][SROW];
    __shared__ __align__(16) short sxl[8][SROW];

    const int tile = blockIdx.x;
    const int b    = blockIdx.y;
    const int n0   = tile * NT;
    const int tid  = threadIdx.x;
    const int wid  = tid >> 6;
    const int lane = tid & 63;

    // B fragment pointers; issue the first (s=0) pair before staging/sync so
    // the main loop starts hot.
    const short* bhp = &g_cbf[0][wid][0][lane][0];   // stride 512 shorts per s
    const short* blp = &g_cbf[1][wid][0][lane][0];
    short8 bh_cur = *(const short8*)(bhp);
    short8 bl_cur = *(const short8*)(blp);

    // ---- Vectorized staging: thread j < 68 owns x elements [8j, 8j+16),
    // builds all 8 shifted windows in registers, writes 16 ds_write_b128.
    if (tid < NCHUNK) {
        const int j  = tid;
        const int e0 = 8 * j;
        const float* __restrict__ src = x + (size_t)b * LIN + n0 + e0;

        float xv[16];
        if (n0 + e0 + 16 <= LIN) {
#pragma unroll
            for (int q = 0; q < 4; ++q) {
                float4 v = *reinterpret_cast<const float4*>(src + 4 * q);
                xv[4 * q + 0] = v.x; xv[4 * q + 1] = v.y;
                xv[4 * q + 2] = v.z; xv[4 * q + 3] = v.w;
            }
        } else {
#pragma unroll
            for (int i = 0; i < 16; ++i) {
                int gi = n0 + e0 + i;
                xv[i] = (gi < LIN) ? src[i] : 0.0f;
            }
        }

        unsigned hd[8], ld[8];   // packed bf16 pairs (low16 = even elem)
#pragma unroll
        for (int i = 0; i < 8; ++i) {
            unsigned h0 = (unsigned short)f2bf(xv[2 * i]);
            unsigned h1 = (unsigned short)f2bf(xv[2 * i + 1]);
            hd[i] = h0 | (h1 << 16);
            unsigned l0 = (unsigned short)f2bf(xv[2 * i]     - bf2f((short)h0));
            unsigned l1 = (unsigned short)f2bf(xv[2 * i + 1] - bf2f((short)h1));
            ld[i] = l0 | (l1 << 16);
        }

#pragma unroll
        for (int c = 0; c < 8; ++c) {
            unsigned wh[4], wl[4];
            if ((c & 1) == 0) {
#pragma unroll
                for (int i = 0; i < 4; ++i) {
                    wh[i] = hd[c / 2 + i];
                    wl[i] = ld[c / 2 + i];
                }
            } else {
#pragma unroll
                for (int i = 0; i < 4; ++i) {
                    int k2 = (c - 1) / 2 + i;
                    wh[i] = (hd[k2] >> 16) | (hd[k2 + 1] << 16);   // v_alignbit
                    wl[i] = (ld[k2] >> 16) | (ld[k2 + 1] << 16);
                }
            }
            uint4 vh = {wh[0], wh[1], wh[2], wh[3]};
            uint4 vl = {wl[0], wl[1], wl[2], wl[3]};
            *reinterpret_cast<uint4*>(&sxh[c][e0]) = vh;
            *reinterpret_cast<uint4*>(&sxl[c][e0]) = vl;
        }
    }
    __syncthreads();

    // ---- MFMA phase
    const int c8    = lane & 7;
    const int abase = 8 * ((lane >> 3) & 1) + 8 * (lane >> 4);
    const short* ah_base = &sxh[c8][abase];
    const short* al_base = &sxl[c8][abase];

    short8 Ah[8], Al[8];
#pragma unroll
    for (int m = 0; m < 8; ++m) {
        Ah[m] = *(const short8*)(ah_base + 16 * m);
        Al[m] = *(const short8*)(al_base + 16 * m);
    }

    f32x4 acc[NSUB];
#pragma unroll
    for (int n = 0; n < NSUB; ++n) {
        f32x4 z = {0.0f, 0.0f, 0.0f, 0.0f};
        acc[n] = z;
    }

#pragma unroll
    for (int s = 0; s < NSTEP; ++s) {
        // Pipeline: issue s+1's B global loads and window ds_reads first.
        short8 bh_nxt, bl_nxt, tah0, tal0, tah1, tal1;
        if (s + 1 < NSTEP) {
            bh_nxt = *(const short8*)(bhp + 512 * (s + 1));
            bl_nxt = *(const short8*)(blp + 512 * (s + 1));
            const int m0 = 2 * s + 8, m1 = 2 * s + 9;
            tah0 = *(const short8*)(ah_base + 16 * m0);
            tal0 = *(const short8*)(al_base + 16 * m0);
            tah1 = *(const short8*)(ah_base + 16 * m1);
            tal1 = *(const short8*)(al_base + 16 * m1);
        }
#pragma unroll
        for (int n = 0; n < NSUB; ++n) {
            const int slot = (2 * s + n) & 7;
            acc[n] = __builtin_amdgcn_mfma_f32_16x16x32_bf16(Ah[slot], bh_cur, acc[n], 0, 0, 0);
            acc[n] = __builtin_amdgcn_mfma_f32_16x16x32_bf16(Al[slot], bh_cur, acc[n], 0, 0, 0);
            acc[n] = __builtin_amdgcn_mfma_f32_16x16x32_bf16(Ah[slot], bl_cur, acc[n], 0, 0, 0);
        }
        if (s + 1 < NSTEP) {
            Ah[(2 * s + 8) & 7] = tah0; Al[(2 * s + 8) & 7] = tal0;
            Ah[(2 * s + 9) & 7] = tah1; Al[(2 * s + 9) & 7] = tal1;
            bh_cur = bh_nxt; bl_cur = bl_nxt;
        }
    }

    // D: col = lane&15 = filter, row = 4*(lane>>4)+r = position offset.
    const int fl = wid * 16 + (lane & 15);
    const size_t rowbase = (size_t)(b * NF + fl) * LOUT;
#pragma unroll
    for (int n = 0; n < NSUB; ++n) {
        const int npos0 = n0 + 16 * n + 4 * (lane >> 4);
#pragma unroll
        for (int r = 0; r < 4; ++r) {
            int np = npos0 + r;
            if (np < LOUT) {
                size_t o = rowbase + np;
                if ((long)o < out_elems) out[o] = acc[n][r];
            }
        }
    }
}

// Complex fallback (folded fp32) in case d_out is interleaved complex.
__global__ __launch_bounds__(TT) void gabor_conv_cplx(const float* __restrict__ x,
                                                      float* __restrict__ out,
                                                      long out_elems) {
    __shared__ float sx[TT + KT];
    const int tile = blockIdx.x, g = blockIdx.y, b = blockIdx.z;
    const int t0 = tile * TT, tid = threadIdx.x;
    const float* __restrict__ xb = x + (size_t)b * LIN;
    for (int i = tid; i < TT + KT - 1; i += TT) {
        int idx = t0 + i;
        sx[i] = (idx < LIN) ? xb[idx] : 0.0f;
    }
    __syncthreads();
    const float* fre = g_filt + g * 16;
    const float* fim = g_filt + KT * NF + g * 16;
    float accre[16], accim[16];
    {
        float x0 = sx[tid], xm = sx[tid + 201];
        const float* c0 = fre;
        const float* cm = fre + 201 * NF;
#pragma unroll
        for (int j = 0; j < 16; ++j) accre[j] = __builtin_fmaf(xm, cm[j], x0 * c0[j]);
#pragma unroll
        for (int j = 0; j < 16; ++j) accim[j] = x0 * fim[j];
    }
#pragma unroll 2
    for (int p = 1; p <= 200; ++p) {
        float x1 = sx[tid + p], x2 = sx[tid + 402 - p];
        float xs = x1 + x2, xd = x1 - x2;
        const float* cr = fre + p * NF;
        const float* ci = fim + p * NF;
#pragma unroll
        for (int j = 0; j < 16; ++j) accre[j] = __builtin_fmaf(xs, cr[j], accre[j]);
#pragma unroll
        for (int j = 0; j < 16; ++j) accim[j] = __builtin_fmaf(xd, ci[j], accim[j]);
    }
    const int t = t0 + tid;
    if (t < LOUT) {
#pragma unroll
        for (int j = 0; j < 16; ++j) {
            size_t o = ((size_t)(b * NF + g * 16 + j) * LOUT + t) * 2;
            if ((long)(o + 1) < out_elems) {
                float2 v; v.x = accre[j]; v.y = accim[j];
                *reinterpret_cast<float2*>(out + o) = v;
            }
        }
    }
}

extern "C" void kernel_launch(void* const* d_in, const int* in_sizes, int n_in,
                              void* d_out, int out_size, void* d_ws, size_t ws_size,
                              hipStream_t stream) {
    const float* x  = (const float*)d_in[0];
    const float* cf = (const float*)d_in[1];
    const float* bw = (const float*)d_in[2];
    float* out = (float*)d_out;
    (void)d_ws; (void)ws_size;

    {
        int n = NF * KP;
        gabor_build_filters<<<(n + 255) / 256, 256, 0, stream>>>(cf, bw);
    }

    const long n_complex = (long)NB * NF * LOUT;
    const bool cplx = ((long)out_size >= 2 * n_complex);

    if (cplx) {
        dim3 grid((LOUT + TT - 1) / TT, NF / 16, NB);
        gabor_conv_cplx<<<grid, TT, 0, stream>>>(x, out, (long)out_size);
    } else {
        dim3 grid((LOUT + NT - 1) / NT, NB);   // (122, 16)
        gabor_conv_mfma<<<grid, TT, 0, stream>>>(x, out, (long)out_size);
    }
}

// Round 8
// 44.220 us; speedup vs baseline: 3.2255x; 1.2486x over previous
//
#include <hip/hip_runtime.h>
#include <math.h>

#define NF    64      // filters
#define KT    402     // taps: arange(-201, 201)
#define KP    416     // padded taps = 13 * 32
#define NSTEP 13      // K-steps of 32
#define LIN   16000
#define LOUT  15599   // LIN - KT + 1
#define NB    16
#define NT    128     // output positions per block (8 subtiles x 16)
#define SPAN  544     // NT + KP data span per block
#define NCHUNK 68     // SPAN / 8 staging chunks
#define SROW  552     // LDS copy-row stride (elems): 1104 B; 8-row b128 reads cover all 32 banks
#define TT    128     // 2 waves per block

typedef __attribute__((ext_vector_type(8))) short short8;   // 8 bf16 (4 VGPR)
typedef __attribute__((ext_vector_type(4))) float f32x4;    // MFMA acc
typedef __attribute__((ext_vector_type(4), aligned(4))) float f32x4u; // 4B-aligned store

// fp32 planes [plane][k][f] for the complex fallback path.
__device__ float g_filt[2 * KT * NF];
// B operand pre-packed in MFMA fragment order: [plane][group][s][lane][j].
// Value = bf16 split of coef(filter = 16*group + (lane&15),
//                            tap    = 8*(lane>>4) + 32*s + j).
__device__ __align__(16) short g_cbf[2][4][NSTEP][64][8];

__device__ __forceinline__ short f2bf(float v) {
    unsigned u = __float_as_uint(v);
    unsigned r = (u + 0x7fffu + ((u >> 16) & 1u)) >> 16;   // RNE
    return (short)r;
}
__device__ __forceinline__ float bf2f(short s) {
    return __uint_as_float(((unsigned)(unsigned short)s) << 16);
}

__global__ void gabor_build_filters(const float* __restrict__ cf,
                                    const float* __restrict__ bw) {
    int idx = blockIdx.x * blockDim.x + threadIdx.x;    // f*KP + k
    if (idx >= NF * KP) return;
    int f = idx / KP;
    int k = idx - f * KP;
    float cre = 0.0f;
    if (k < KT) {
        float t = (float)(k - 201);
        float b = bw[f];
        float env = expf(-(t * t) / (2.0f * b * b)) / (sqrtf(2.0f * (float)M_PI) * b);
        float s, c;
        sincosf(cf[f] * t, &s, &c);
        cre = env * c;
        g_filt[k * NF + f]           = cre;      // re plane (fallback)
        g_filt[KT * NF + k * NF + f] = env * s;  // im plane (fallback)
    }
    short hi = f2bf(cre);
    short lo = f2bf(cre - bf2f(hi));
    // scatter into fragment order: lane = (f&15) | q<<4, with k = 32s + 8q + j
    int g = f >> 4;
    int s = k >> 5;
    int q = (k >> 3) & 3;
    int j = k & 7;
    int l = (f & 15) | (q << 4);
    g_cbf[0][g][s][l][j] = hi;
    g_cbf[1][g][s][l][j] = lo;
}

// MFMA implicit GEMM, real part only. Per block: 128 positions x ALL 64
// filters x batch b; 2 waves, wave w = position-subtiles 4w..4w+3.
// Each wave processes all 4 filter-groups per A-fragment, so one LDS
// ds_read_b128 pair feeds 12 MFMAs (R7 post-mortem: compiler remats A-window
// reads from LDS regardless of source pipelining -> make the remat schedule
// itself MFMA-bound instead of fighting the scheduler).
// A (Hankel of x) from LDS via 8 shifted bf16 copies (copy c holds element i
// at index i-c -> every fragment one aligned ds_read_b128).
// 3-term bf16 split (Ah*Bh + Al*Bh + Ah*Bl) emulates fp32.
__global__ __launch_bounds__(TT, 3) void gabor_conv_mfma(const float* __restrict__ x,
                                                         float* __restrict__ out,
                                                         long out_elems) {
    __shared__ __align__(16) short sxh[8][SROW];
    __shared__ __align__(16) short sxl[8][SROW];

    const int tile = blockIdx.x;
    const int b    = blockIdx.y;
    const int n0   = tile * NT;
    const int tid  = threadIdx.x;
    const int wid  = tid >> 6;      // 0..1
    const int lane = tid & 63;

    // ---- Vectorized staging: thread j < 68 owns x elements [8j, 8j+16),
    // builds all 8 shifted windows in registers, writes 16 ds_write_b128.
    if (tid < NCHUNK) {
        const int j  = tid;
        const int e0 = 8 * j;
        const float* __restrict__ src = x + (size_t)b * LIN + n0 + e0;

        float xv[16];
        if (n0 + e0 + 16 <= LIN) {
#pragma unroll
            for (int q = 0; q < 4; ++q) {
                float4 v = *reinterpret_cast<const float4*>(src + 4 * q);
                xv[4 * q + 0] = v.x; xv[4 * q + 1] = v.y;
                xv[4 * q + 2] = v.z; xv[4 * q + 3] = v.w;
            }
        } else {
#pragma unroll
            for (int i = 0; i < 16; ++i) {
                int gi = n0 + e0 + i;
                xv[i] = (gi < LIN) ? src[i] : 0.0f;
            }
        }

        unsigned hd[8], ld[8];   // packed bf16 pairs (low16 = even elem)
#pragma unroll
        for (int i = 0; i < 8; ++i) {
            unsigned h0 = (unsigned short)f2bf(xv[2 * i]);
            unsigned h1 = (unsigned short)f2bf(xv[2 * i + 1]);
            hd[i] = h0 | (h1 << 16);
            unsigned l0 = (unsigned short)f2bf(xv[2 * i]     - bf2f((short)h0));
            unsigned l1 = (unsigned short)f2bf(xv[2 * i + 1] - bf2f((short)h1));
            ld[i] = l0 | (l1 << 16);
        }

#pragma unroll
        for (int c = 0; c < 8; ++c) {
            unsigned wh[4], wl[4];
            if ((c & 1) == 0) {
#pragma unroll
                for (int i = 0; i < 4; ++i) {
                    wh[i] = hd[c / 2 + i];
                    wl[i] = ld[c / 2 + i];
                }
            } else {
#pragma unroll
                for (int i = 0; i < 4; ++i) {
                    int k2 = (c - 1) / 2 + i;
                    wh[i] = (hd[k2] >> 16) | (hd[k2 + 1] << 16);   // v_alignbit
                    wl[i] = (ld[k2] >> 16) | (ld[k2 + 1] << 16);
                }
            }
            uint4 vh = {wh[0], wh[1], wh[2], wh[3]};
            uint4 vl = {wl[0], wl[1], wl[2], wl[3]};
            *reinterpret_cast<uint4*>(&sxh[c][e0]) = vh;
            *reinterpret_cast<uint4*>(&sxl[c][e0]) = vl;
        }
    }
    __syncthreads();

    // ---- MFMA phase
    const int c8    = lane & 7;
    const int abase = 8 * ((lane >> 3) & 1) + 8 * (lane >> 4);
    const short* ah_base = &sxh[c8][abase];
    const short* al_base = &sxl[c8][abase];
    const int subbase = wid * 4;    // this wave's first position-subtile

    f32x4 acc[4][4];                // [n][group], all-static indexing
#pragma unroll
    for (int n = 0; n < 4; ++n)
#pragma unroll
        for (int g = 0; g < 4; ++g) {
            f32x4 z = {0.0f, 0.0f, 0.0f, 0.0f};
            acc[n][g] = z;
        }

#pragma unroll
    for (int s = 0; s < NSTEP; ++s) {
        short8 bh[4], bl[4];
#pragma unroll
        for (int g = 0; g < 4; ++g) {
            bh[g] = *(const short8*)(&g_cbf[0][g][s][lane][0]);
            bl[g] = *(const short8*)(&g_cbf[1][g][s][lane][0]);
        }
#pragma unroll
        for (int n = 0; n < 4; ++n) {
            const int m = subbase + n + 2 * s;
            short8 ah = *(const short8*)(ah_base + 16 * m);
            short8 al = *(const short8*)(al_base + 16 * m);
#pragma unroll
            for (int g = 0; g < 4; ++g) {
                acc[n][g] = __builtin_amdgcn_mfma_f32_16x16x32_bf16(ah, bh[g], acc[n][g], 0, 0, 0);
                acc[n][g] = __builtin_amdgcn_mfma_f32_16x16x32_bf16(al, bh[g], acc[n][g], 0, 0, 0);
                acc[n][g] = __builtin_amdgcn_mfma_f32_16x16x32_bf16(ah, bl[g], acc[n][g], 0, 0, 0);
            }
        }
    }

    // D: col = lane&15 = filter-in-group, rows 4*(lane>>4)+0..3 = consecutive
    // positions -> one dwordx4 store (4B-aligned type; LOUT is odd).
    const int r0 = 4 * (lane >> 4);
#pragma unroll
    for (int n = 0; n < 4; ++n) {
        const int np = n0 + 16 * (subbase + n) + r0;
#pragma unroll
        for (int g = 0; g < 4; ++g) {
            const int f = 16 * g + (lane & 15);
            const size_t o = (size_t)(b * NF + f) * LOUT + np;
            if (np + 3 < LOUT && (long)(o + 3) < out_elems) {
                *reinterpret_cast<f32x4u*>(out + o) = acc[n][g];
            } else {
#pragma unroll
                for (int r = 0; r < 4; ++r)
                    if (np + r < LOUT && (long)(o + r) < out_elems)
                        out[o + r] = acc[n][g][r];
            }
        }
    }
}

// Complex fallback (folded fp32) in case d_out is interleaved complex.
__global__ __launch_bounds__(256) void gabor_conv_cplx(const float* __restrict__ x,
                                                       float* __restrict__ out,
                                                       long out_elems) {
    __shared__ float sx[256 + KT];
    const int tile = blockIdx.x, g = blockIdx.y, b = blockIdx.z;
    const int t0 = tile * 256, tid = threadIdx.x;
    const float* __restrict__ xb = x + (size_t)b * LIN;
    for (int i = tid; i < 256 + KT - 1; i += 256) {
        int idx = t0 + i;
        sx[i] = (idx < LIN) ? xb[idx] : 0.0f;
    }
    __syncthreads();
    const float* fre = g_filt + g * 16;
    const float* fim = g_filt + KT * NF + g * 16;
    float accre[16], accim[16];
    {
        float x0 = sx[tid], xm = sx[tid + 201];
        const float* c0 = fre;
        const float* cm = fre + 201 * NF;
#pragma unroll
        for (int j = 0; j < 16; ++j) accre[j] = __builtin_fmaf(xm, cm[j], x0 * c0[j]);
#pragma unroll
        for (int j = 0; j < 16; ++j) accim[j] = x0 * fim[j];
    }
#pragma unroll 2
    for (int p = 1; p <= 200; ++p) {
        float x1 = sx[tid + p], x2 = sx[tid + 402 - p];
        float xs = x1 + x2, xd = x1 - x2;
        const float* cr = fre + p * NF;
        const float* ci = fim + p * NF;
#pragma unroll
        for (int j = 0; j < 16; ++j) accre[j] = __builtin_fmaf(xs, cr[j], accre[j]);
#pragma unroll
        for (int j = 0; j < 16; ++j) accim[j] = __builtin_fmaf(xd, ci[j], accim[j]);
    }
    const int t = t0 + tid;
    if (t < LOUT) {
#pragma unroll
        for (int j = 0; j < 16; ++j) {
            size_t o = ((size_t)(b * NF + g * 16 + j) * LOUT + t) * 2;
            if ((long)(o + 1) < out_elems) {
                float2 v; v.x = accre[j]; v.y = accim[j];
                *reinterpret_cast<float2*>(out + o) = v;
            }
        }
    }
}

extern "C" void kernel_launch(void* const* d_in, const int* in_sizes, int n_in,
                              void* d_out, int out_size, void* d_ws, size_t ws_size,
                              hipStream_t stream) {
    const float* x  = (const float*)d_in[0];
    const float* cf = (const float*)d_in[1];
    const float* bw = (const float*)d_in[2];
    float* out = (float*)d_out;
    (void)d_ws; (void)ws_size;

    {
        int n = NF * KP;
        gabor_build_filters<<<(n + 255) / 256, 256, 0, stream>>>(cf, bw);
    }

    const long n_complex = (long)NB * NF * LOUT;
    const bool cplx = ((long)out_size >= 2 * n_complex);

    if (cplx) {
        dim3 grid((LOUT + 255) / 256, NF / 16, NB);
        gabor_conv_cplx<<<grid, 256, 0, stream>>>(x, out, (long)out_size);
    } else {
        dim3 grid((LOUT + NT - 1) / NT, NB);   // (122, 16)
        gabor_conv_mfma<<<grid, TT, 0, stream>>>(x, out, (long)out_size);
    }
}